// Round 5
// baseline (762.335 us; speedup 1.0000x reference)
//
#include <hip/hip_runtime.h>

// VQ nearest-codeword argmin. N=262144 rows (D=64 f32), K=512, out int32.
//
// R5 structure: prep kernel (A/S per row exact; codebook bf16 pre-swizzled
// image + norms) -> main kernel: z tile bf16 in LDS, cb chunks DMA'd via
// global_load_lds, two-sweep MFMA (sweep1 = min only, sweep2 = recompute +
// candidate test + exact f32 refine). Numpy rounding contract (absmax=0 in
// R1/R2/R4): dist = fl(fl(A - 2*dot) + C) contract-off, A = numpy 8-acc
// pairwise. Tie-break: (dist_bits<<32)|k u64 atomicMin (dist>0 => monotone).
//
// Margin: |e|<1/512, bf16 RNE => |core_bf - core| <= S*2^-16 each side;
// threshold = min_core + S*2^-15 + 1e-4 (validated R4). Sweep2 recomputes
// bit-identical cores, so capture condition is exactly R4's.

typedef __attribute__((ext_vector_type(8))) short bf16x8;
typedef __attribute__((ext_vector_type(4))) float f32x4;

constexpr int DCB = 64;

// ws layout (bytes); total ~2.17 MB
constexpr size_t WS_A     = 0;                    // f32[262144] exact ||z||^2
constexpr size_t WS_S     = 1048576;              // f32[262144] sum|z|
constexpr size_t WS_CB    = 2097152;              // 64 KiB bf16 pre-swz image
constexpr size_t WS_CNORM = 2097152 + 65536;      // f32[512]

static __device__ inline unsigned short f2bf(float f) {  // f32->bf16 RNE
  unsigned u = __float_as_uint(f);
  return (unsigned short)((u + 0x7FFFu + ((u >> 16) & 1u)) >> 16);
}
static __device__ inline unsigned fkey(float x) {  // order-preserving f32->u32
  unsigned u = __float_as_uint(x);
  return ((int)u < 0) ? ~u : (u | 0x80000000u);
}
static __device__ inline float funkey(unsigned k) {
  return (k & 0x80000000u) ? __uint_as_float(k ^ 0x80000000u)
                           : __uint_as_float(~k);
}

// swizzled LDS byte offset: row-major [*][64] bf16 (128 B rows), XOR bits 4-6
#define SWZ(row, byteInRow) (((row) << 7) + ((byteInRow) ^ (((row) & 7) << 4)))

// ---------------- prep kernel ----------------
__global__ __launch_bounds__(256) void vq_prep_kernel(
    const float* __restrict__ z, const float* __restrict__ cb,
    unsigned char* __restrict__ ws, int N)
{
  const int tid = threadIdx.x;
  const int row = blockIdx.x * 256 + tid;
  float* wsA = (float*)(ws + WS_A);
  float* wsS = (float*)(ws + WS_S);

  if (row < N) {
    const float4* q4 = reinterpret_cast<const float4*>(z + (size_t)row * DCB);
    float4 q[16];
    #pragma unroll
    for (int j = 0; j < 16; ++j) q[j] = q4[j];
    float A;
    {
      #pragma clang fp contract(off)
      float r0 = q[0].x*q[0].x, r1 = q[0].y*q[0].y, r2 = q[0].z*q[0].z, r3 = q[0].w*q[0].w;
      float r4 = q[1].x*q[1].x, r5 = q[1].y*q[1].y, r6 = q[1].z*q[1].z, r7 = q[1].w*q[1].w;
      #pragma unroll
      for (int a = 1; a < 8; ++a) {
        r0 += q[2*a].x*q[2*a].x;     r1 += q[2*a].y*q[2*a].y;
        r2 += q[2*a].z*q[2*a].z;     r3 += q[2*a].w*q[2*a].w;
        r4 += q[2*a+1].x*q[2*a+1].x; r5 += q[2*a+1].y*q[2*a+1].y;
        r6 += q[2*a+1].z*q[2*a+1].z; r7 += q[2*a+1].w*q[2*a+1].w;
      }
      A = ((r0 + r1) + (r2 + r3)) + ((r4 + r5) + (r6 + r7));
    }
    wsA[row] = A;
    float s0 = 0.f, s1 = 0.f, s2 = 0.f, s3 = 0.f;
    #pragma unroll
    for (int j = 0; j < 16; ++j) {
      s0 += fabsf(q[j].x); s1 += fabsf(q[j].y);
      s2 += fabsf(q[j].z); s3 += fabsf(q[j].w);
    }
    wsS[row] = (s0 + s1) + (s2 + s3);
  }

  if (blockIdx.x < 2) {   // codebook prep: 512 codewords over blocks 0,1
    const int k = blockIdx.x * 256 + tid;
    const float4* e4 = reinterpret_cast<const float4*>(cb + (size_t)k * DCB);
    float4 e[16];
    #pragma unroll
    for (int j = 0; j < 16; ++j) e[j] = e4[j];
    float s0 = 0.f, s1 = 0.f, s2 = 0.f, s3 = 0.f;
    #pragma unroll
    for (int j = 0; j < 16; ++j) {
      s0 = fmaf(e[j].x, e[j].x, s0); s1 = fmaf(e[j].y, e[j].y, s1);
      s2 = fmaf(e[j].z, e[j].z, s2); s3 = fmaf(e[j].w, e[j].w, s3);
    }
    ((float*)(ws + WS_CNORM))[k] = (s0 + s1) + (s2 + s3);

    const int r = k & 255;
    unsigned char* img = ws + WS_CB + (size_t)(k >> 8) * 32768 + (size_t)r * 128;
    #pragma unroll
    for (int c16 = 0; c16 < 8; ++c16) {   // 16B chunk -> pre-swizzled slot
      uint4 wv;
      wv.x = (unsigned)f2bf(e[2*c16].x)   | ((unsigned)f2bf(e[2*c16].y)   << 16);
      wv.y = (unsigned)f2bf(e[2*c16].z)   | ((unsigned)f2bf(e[2*c16].w)   << 16);
      wv.z = (unsigned)f2bf(e[2*c16+1].x) | ((unsigned)f2bf(e[2*c16+1].y) << 16);
      wv.w = (unsigned)f2bf(e[2*c16+1].z) | ((unsigned)f2bf(e[2*c16+1].w) << 16);
      *reinterpret_cast<uint4*>(img + ((c16 ^ (r & 7)) << 4)) = wv;
    }
  }
}

// ---------------- main kernel ----------------
static __device__ __attribute__((noinline)) void refine_site(
    int row0, int row_local, int k,
    const float* __restrict__ z, const float* __restrict__ cb,
    const float* __restrict__ wsA, const float* cnormS,
    unsigned long long* bestS)
{
  const float* zr = z + (size_t)(row0 + row_local) * DCB;
  const float* e  = cb + (size_t)k * DCB;
  float d0 = 0.f, d1 = 0.f, d2 = 0.f, d3 = 0.f;
  #pragma unroll
  for (int j = 0; j < DCB; j += 4) {
    d0 = fmaf(zr[j + 0], e[j + 0], d0);
    d1 = fmaf(zr[j + 1], e[j + 1], d1);
    d2 = fmaf(zr[j + 2], e[j + 2], d2);
    d3 = fmaf(zr[j + 3], e[j + 3], d3);
  }
  const float dot = (d0 + d1) + (d2 + d3);
  const float A  = wsA[row0 + row_local];
  const float Ck = cnormS[k];
  float dist;
  {
    #pragma clang fp contract(off)
    dist = (A - 2.0f * dot) + Ck;   // two separately-rounded f32 ops
  }
  unsigned long long packed =
      ((unsigned long long)__float_as_uint(dist) << 32) | (unsigned)k;
  atomicMin(bestS + row_local, packed);
}

static __device__ inline void dma_chunk(const unsigned char* src,
                                        unsigned short* cbBf, int wv, int lane)
{
  #pragma unroll
  for (int q = 0; q < 4; ++q) {        // 8 waves x 4 slabs x 1 KiB = 32 KiB
    const int slab = wv * 4 + q;
    const unsigned char* gp = src + slab * 1024 + lane * 16;
    char* lp = (char*)cbBf + slab * 1024;   // wave-uniform; HW adds lane*16
    __builtin_amdgcn_global_load_lds(
        (const __attribute__((address_space(1))) unsigned int*)gp,
        (__attribute__((address_space(3))) unsigned int*)lp, 16, 0, 0);
  }
}

template <bool REFINE>
static __device__ inline void sweep_chunk(
    int cbase, const unsigned short* cbBf, const float* cnormS,
    const bf16x8 afr[2][2], int rw, int cw, int g, int lm,
    float mA[4], float mB[4], const float thrA[4], const float thrB[4],
    int row0, const float* z, const float* cb, const float* wsA,
    unsigned long long* bestS)
{
  #pragma unroll
  for (int ct = 0; ct < 8; ++ct) {
    const int rowc = cw * 128 + ct * 16 + lm;
    const bf16x8 b0 = *reinterpret_cast<const bf16x8*>(
        (const char*)cbBf + SWZ(rowc, 16 * g));
    const bf16x8 b1 = *reinterpret_cast<const bf16x8*>(
        (const char*)cbBf + SWZ(rowc, 16 * g + 64));
    const float Cc = cnormS[cbase + rowc];
    f32x4 accA = (f32x4)0.0f, accB = (f32x4)0.0f;
    accA = __builtin_amdgcn_mfma_f32_16x16x32_bf16(afr[0][0], b0, accA, 0, 0, 0);
    accA = __builtin_amdgcn_mfma_f32_16x16x32_bf16(afr[0][1], b1, accA, 0, 0, 0);
    accB = __builtin_amdgcn_mfma_f32_16x16x32_bf16(afr[1][0], b0, accB, 0, 0, 0);
    accB = __builtin_amdgcn_mfma_f32_16x16x32_bf16(afr[1][1], b1, accB, 0, 0, 0);
    #pragma unroll
    for (int i = 0; i < 4; ++i) {
      const float vA = fmaf(-2.0f, accA[i], Cc);
      const float vB = fmaf(-2.0f, accB[i], Cc);
      if (!REFINE) {
        mA[i] = fminf(mA[i], vA);
        mB[i] = fminf(mB[i], vB);
      } else {
        const int kk = cbase + rowc;
        if (vA <= thrA[i])
          refine_site(row0, rw * 32 + (g << 2) + i, kk, z, cb, wsA, cnormS, bestS);
        if (vB <= thrB[i])
          refine_site(row0, rw * 32 + 16 + (g << 2) + i, kk, z, cb, wsA, cnormS, bestS);
      }
    }
  }
}

__global__ __launch_bounds__(512, 6) void vq_main_kernel(
    const float* __restrict__ z, const float* __restrict__ cb,
    const unsigned char* __restrict__ ws, int* __restrict__ out, int N)
{
  __shared__ unsigned short cbBf[256 * DCB];   // 32 KiB cb chunk (bf16, swz)
  __shared__ unsigned short zBf[128 * DCB];    // 16 KiB z tile (bf16, swz)
  __shared__ float cnormS[512];                // 2 KiB
  __shared__ float thrS[128];
  __shared__ unsigned rowminS[128];
  __shared__ unsigned long long bestS[128];    // total LDS = 53248 B

  const int tid = threadIdx.x;
  const int lane = tid & 63, wv = tid >> 6;
  const int rw = wv & 3, cw = wv >> 2;
  const int g = lane >> 4, lm = lane & 15;
  const int row0 = blockIdx.x * 128;

  const float* wsA = (const float*)(ws + WS_A);
  const float* wsS = (const float*)(ws + WS_S);
  const unsigned char* wsCb = ws + WS_CB;
  const float* wsCn = (const float*)(ws + WS_CNORM);

  // Phase 0: init, stage z (bf16 swz), cnorm -> LDS, DMA cb chunk 0
  if (tid < 128) { rowminS[tid] = 0xFFFFFFFFu; bestS[tid] = ~0ull; }
  cnormS[tid] = wsCn[tid & 511];
  {
    const float4* zg = reinterpret_cast<const float4*>(z + (size_t)row0 * DCB);
    #pragma unroll
    for (int ii = 0; ii < 4; ++ii) {          // 2048 float4 / 512 threads
      const int m = tid + (ii << 9);
      const int row = m >> 4, c4 = m & 15;
      const float4 f = zg[m];
      uint2 u;
      u.x = (unsigned)f2bf(f.x) | ((unsigned)f2bf(f.y) << 16);
      u.y = (unsigned)f2bf(f.z) | ((unsigned)f2bf(f.w) << 16);
      *reinterpret_cast<uint2*>((char*)zBf + SWZ(row, c4 * 8)) = u;
    }
  }
  dma_chunk(wsCb, cbBf, wv, lane);            // chunk 0
  __syncthreads();                            // drains vmcnt + lgkm

  // A fragments (held across both sweeps)
  bf16x8 afr[2][2];
  #pragma unroll
  for (int rt = 0; rt < 2; ++rt) {
    const int row = rw * 32 + rt * 16 + lm;
    #pragma unroll
    for (int s = 0; s < 2; ++s)
      afr[rt][s] = *reinterpret_cast<const bf16x8*>(
          (const char*)zBf + SWZ(row, 16 * g + 64 * s));
  }

  float mA[4], mB[4], thrA[4], thrB[4];
  #pragma unroll
  for (int i = 0; i < 4; ++i) {
    mA[i] = __builtin_inff(); mB[i] = __builtin_inff();
    thrA[i] = 0.f; thrB[i] = 0.f;
  }

  // Sweep 1, chunk 0 (min only)
  sweep_chunk<false>(0, cbBf, cnormS, afr, rw, cw, g, lm,
                     mA, mB, thrA, thrB, row0, z, cb, wsA, bestS);
  __syncthreads();                            // cbBf readers done
  dma_chunk(wsCb + 32768, cbBf, wv, lane);    // chunk 1
  __syncthreads();
  // Sweep 1, chunk 1
  sweep_chunk<false>(256, cbBf, cnormS, afr, rw, cw, g, lm,
                     mA, mB, thrA, thrB, row0, z, cb, wsA, bestS);

  // Cross-lane + cross-wave min reduce
  #pragma unroll
  for (int mask = 1; mask <= 8; mask <<= 1) {
    #pragma unroll
    for (int i = 0; i < 4; ++i) {
      mA[i] = fminf(mA[i], __shfl_xor(mA[i], mask));
      mB[i] = fminf(mB[i], __shfl_xor(mB[i], mask));
    }
  }
  if (lm == 0) {
    #pragma unroll
    for (int i = 0; i < 4; ++i) {
      atomicMin(&rowminS[rw * 32 + (g << 2) + i], fkey(mA[i]));
      atomicMin(&rowminS[rw * 32 + 16 + (g << 2) + i], fkey(mB[i]));
    }
  }
  __syncthreads();

  // Per-row threshold
  if (tid < 128) {
    const float mn = funkey(rowminS[tid]);
    thrS[tid] = mn + fmaf(wsS[row0 + tid], 3.0517578125e-5f, 1e-4f);
  }
  __syncthreads();
  #pragma unroll
  for (int i = 0; i < 4; ++i) {
    thrA[i] = thrS[rw * 32 + (g << 2) + i];
    thrB[i] = thrS[rw * 32 + 16 + (g << 2) + i];
  }

  // Sweep 2, chunk 1 (still resident), then restage chunk 0
  sweep_chunk<true>(256, cbBf, cnormS, afr, rw, cw, g, lm,
                    mA, mB, thrA, thrB, row0, z, cb, wsA, bestS);
  __syncthreads();
  dma_chunk(wsCb, cbBf, wv, lane);            // chunk 0 again
  __syncthreads();
  sweep_chunk<true>(0, cbBf, cnormS, afr, rw, cw, g, lm,
                    mA, mB, thrA, thrB, row0, z, cb, wsA, bestS);
  __syncthreads();                            // bestS atomics visible

  if (tid < 128) out[row0 + tid] = (int)(bestS[tid] & 0xFFFFFFFFull);
}

extern "C" void kernel_launch(void* const* d_in, const int* in_sizes, int n_in,
                              void* d_out, int out_size, void* d_ws, size_t ws_size,
                              hipStream_t stream) {
  const float* z  = (const float*)d_in[0];   // [N, 64] f32
  const float* cb = (const float*)d_in[1];   // [512, 64] f32
  int* out = (int*)d_out;                    // [N] int32 indices
  unsigned char* ws = (unsigned char*)d_ws;  // needs ~2.17 MB

  const int N = in_sizes[0] / DCB;           // 262144

  vq_prep_kernel<<<(N + 255) / 256, 256, 0, stream>>>(z, cb, ws, N);
  vq_main_kernel<<<N / 128, 512, 0, stream>>>(z, cb, ws, out, N);
}

// Round 6
// 163.105 us; speedup vs baseline: 4.6739x; 4.6739x over previous
//
#include <hip/hip_runtime.h>

// VQ nearest-codeword argmin. N=262144 rows (D=64 f32), K=512, out int32.
//
// R6: prep kernel (codebook -> bf16 pre-swizzled LDS image + f32 norms) ->
// main kernel: whole 64 KiB codebook DMA'd to LDS once, ONE barrier, then
// each wave independently handles 32 rows x 512 codewords:
//   sweep1: MFMA bf16 dots, fold fmax(dot)        (no cnorm needed)
//   reduce: 16-lane shfl fmax -> per-row max dot
//   thr = -2*dmax + CMAX + S*2^-15 + 1e-4         (>= validated R4/R5 thr)
//   sweep2: recompute (bit-identical), candidates <= thr -> <=4 regs/lane
//           + per-wave LDS overflow queue (immediate-refine fallback)
//   refine: exact f32, numpy rounding contract (absmax=0 in R1/R2/R4/R5):
//           dist = fl(fl(A - 2*dot) + C) contract-off; A = numpy 8-acc
//           pairwise. Tie: (dist_bits<<32)|k u64 atomicMin (wave-private).
// CMAX = 64*(1/512)^2 = 2.44140625e-4 (codebook ~ uniform(-1/512,1/512));
// min(core) <= -2*dmax + CMAX so the enlarged threshold keeps the R4/R5
// capture guarantee. Margin: |core_bf - core| <= S*2^-16 per side.

typedef __attribute__((ext_vector_type(8))) short bf16x8;
typedef __attribute__((ext_vector_type(4))) float f32x4;

constexpr int DCB = 64;
constexpr size_t WS_CB    = 0;        // 64 KiB bf16 pre-swizzled image
constexpr size_t WS_CNORM = 65536;    // f32[512]

static __device__ inline unsigned short f2bf(float f) {  // f32->bf16 RNE
  unsigned u = __float_as_uint(f);
  return (unsigned short)((u + 0x7FFFu + ((u >> 16) & 1u)) >> 16);
}

// swizzled byte offset in a [rows][64 bf16] image (128 B rows), XOR bits 4-6
#define SWZ(row, b) (((row) << 7) + ((b) ^ (((row) & 7) << 4)))

// ---------------- prep kernel: codebook image + norms ----------------
__global__ __launch_bounds__(256) void vq_prep_kernel(
    const float* __restrict__ cb, unsigned char* __restrict__ ws)
{
  const int k = blockIdx.x * 256 + threadIdx.x;   // 0..511
  const float4* e4 = reinterpret_cast<const float4*>(cb + (size_t)k * DCB);
  float4 e[16];
  #pragma unroll
  for (int j = 0; j < 16; ++j) e[j] = e4[j];
  float s0 = 0.f, s1 = 0.f, s2 = 0.f, s3 = 0.f;
  #pragma unroll
  for (int j = 0; j < 16; ++j) {
    s0 = fmaf(e[j].x, e[j].x, s0); s1 = fmaf(e[j].y, e[j].y, s1);
    s2 = fmaf(e[j].z, e[j].z, s2); s3 = fmaf(e[j].w, e[j].w, s3);
  }
  ((float*)(ws + WS_CNORM))[k] = (s0 + s1) + (s2 + s3);

  const int r = k & 255;
  unsigned char* img = ws + WS_CB + (size_t)(k >> 8) * 32768 + (size_t)r * 128;
  #pragma unroll
  for (int c16 = 0; c16 < 8; ++c16) {      // 16B chunk -> pre-swizzled slot
    uint4 w;
    w.x = (unsigned)f2bf(e[2*c16].x)   | ((unsigned)f2bf(e[2*c16].y)   << 16);
    w.y = (unsigned)f2bf(e[2*c16].z)   | ((unsigned)f2bf(e[2*c16].w)   << 16);
    w.z = (unsigned)f2bf(e[2*c16+1].x) | ((unsigned)f2bf(e[2*c16+1].y) << 16);
    w.w = (unsigned)f2bf(e[2*c16+1].z) | ((unsigned)f2bf(e[2*c16+1].w) << 16);
    *reinterpret_cast<uint4*>(img + ((c16 ^ (r & 7)) << 4)) = w;
  }
}

// ---------------- main kernel ----------------
static __device__ inline void refine_rk(
    int row0, int row_local, int k,
    const float* __restrict__ z, const float* __restrict__ cb,
    const float* ArowSp, const float* cnormSp, unsigned long long* bestSp)
{
  const float* zr = z + (size_t)(row0 + row_local) * DCB;
  const float* e  = cb + (size_t)k * DCB;
  float d0 = 0.f, d1 = 0.f, d2 = 0.f, d3 = 0.f;
  #pragma unroll
  for (int j = 0; j < DCB; j += 4) {
    d0 = fmaf(zr[j + 0], e[j + 0], d0);
    d1 = fmaf(zr[j + 1], e[j + 1], d1);
    d2 = fmaf(zr[j + 2], e[j + 2], d2);
    d3 = fmaf(zr[j + 3], e[j + 3], d3);
  }
  const float dot = (d0 + d1) + (d2 + d3);
  const float A  = ArowSp[row_local];
  const float Ck = cnormSp[k];
  float dist;
  {
    #pragma clang fp contract(off)
    dist = (A - 2.0f * dot) + Ck;   // two separately-rounded f32 ops
  }
  unsigned long long packed =
      ((unsigned long long)__float_as_uint(dist) << 32) | (unsigned)k;
  atomicMin(bestSp + row_local, packed);
}

static __device__ inline bf16x8 pack8(float4 a, float4 b) {
  bf16x8 r;
  r[0] = (short)f2bf(a.x); r[1] = (short)f2bf(a.y);
  r[2] = (short)f2bf(a.z); r[3] = (short)f2bf(a.w);
  r[4] = (short)f2bf(b.x); r[5] = (short)f2bf(b.y);
  r[6] = (short)f2bf(b.z); r[7] = (short)f2bf(b.w);
  return r;
}

__global__ __launch_bounds__(512, 4) void vq_main_kernel(
    const float* __restrict__ z, const float* __restrict__ cb,
    const unsigned char* __restrict__ ws, int* __restrict__ out, int N)
{
  __shared__ unsigned short cbBf[512 * DCB];    // 64 KiB whole codebook (swz)
  __shared__ float cnormS[512];                 // 2 KiB
  __shared__ float ArowS[256];                  // 1 KiB exact pairwise ||z||^2
  __shared__ float SrowS[256];                  // 1 KiB sum|z|
  __shared__ unsigned long long bestS[256];     // 2 KiB packed (dist,k)
  __shared__ unsigned ovfCnt[8];                // per-wave overflow count
  __shared__ unsigned ovfQ[8][64];              // per-wave overflow queue
  // total LDS = 73,760 B -> 2 blocks/CU

  const int tid = threadIdx.x;
  const int lane = tid & 63, wv = tid >> 6;
  const int g = lane >> 4, lm = lane & 15;
  const int row0 = blockIdx.x * 256;

  // ---- Phase 0 (single barrier at the end) ----
  // (a) DMA whole codebook image: 64 slabs of 1 KiB, 8 per wave
  {
    const unsigned char* src = ws + WS_CB;
    #pragma unroll
    for (int q = 0; q < 8; ++q) {
      const int slab = wv * 8 + q;
      const unsigned char* gp = src + slab * 1024 + lane * 16;
      char* lp = (char*)cbBf + slab * 1024;  // wave-uniform; HW adds lane*16
      __builtin_amdgcn_global_load_lds(
          (const __attribute__((address_space(1))) unsigned int*)gp,
          (__attribute__((address_space(3))) unsigned int*)lp, 16, 0, 0);
    }
  }
  // (b) cnorm -> LDS; init bestS / ovfCnt
  cnormS[tid] = ((const float*)(ws + WS_CNORM))[tid];
  if (tid < 256) bestS[tid] = ~0ull;
  if (tid < 8) ovfCnt[tid] = 0u;
  // (c) exact pairwise A (numpy 8-acc) + S = sum|z|, threads 0..255
  if (tid < 256) {
    const float4* q4 = reinterpret_cast<const float4*>(z + (size_t)(row0 + tid) * DCB);
    float4 q[16];
    #pragma unroll
    for (int j = 0; j < 16; ++j) q[j] = q4[j];
    float A;
    {
      #pragma clang fp contract(off)
      float r0 = q[0].x*q[0].x, r1 = q[0].y*q[0].y, r2 = q[0].z*q[0].z, r3 = q[0].w*q[0].w;
      float r4 = q[1].x*q[1].x, r5 = q[1].y*q[1].y, r6 = q[1].z*q[1].z, r7 = q[1].w*q[1].w;
      #pragma unroll
      for (int a = 1; a < 8; ++a) {
        r0 += q[2*a].x*q[2*a].x;     r1 += q[2*a].y*q[2*a].y;
        r2 += q[2*a].z*q[2*a].z;     r3 += q[2*a].w*q[2*a].w;
        r4 += q[2*a+1].x*q[2*a+1].x; r5 += q[2*a+1].y*q[2*a+1].y;
        r6 += q[2*a+1].z*q[2*a+1].z; r7 += q[2*a+1].w*q[2*a+1].w;
      }
      A = ((r0 + r1) + (r2 + r3)) + ((r4 + r5) + (r6 + r7));
    }
    ArowS[tid] = A;
    float s0 = 0.f, s1 = 0.f, s2 = 0.f, s3 = 0.f;
    #pragma unroll
    for (int j = 0; j < 16; ++j) {
      s0 += fabsf(q[j].x); s1 += fabsf(q[j].y);
      s2 += fabsf(q[j].z); s3 += fabsf(q[j].w);
    }
    SrowS[tid] = (s0 + s1) + (s2 + s3);
  }
  // (d) A-fragments from global f32 (rows L2-hot after (c)), convert in-reg
  bf16x8 afr[2][2];
  #pragma unroll
  for (int rt = 0; rt < 2; ++rt) {
    const float* zrow = z + (size_t)(row0 + wv * 32 + rt * 16 + lm) * DCB;
    #pragma unroll
    for (int s = 0; s < 2; ++s) {
      const float4 u0 = *reinterpret_cast<const float4*>(zrow + 32 * s + 8 * g);
      const float4 u1 = *reinterpret_cast<const float4*>(zrow + 32 * s + 8 * g + 4);
      afr[rt][s] = pack8(u0, u1);
    }
  }
  __syncthreads();   // drains DMA (vmcnt) + LDS writes; the ONLY block barrier

  // ---- Sweep 1: fold max(dot) per (rt,i) ----
  float dmax[2][4];
  #pragma unroll
  for (int rt = 0; rt < 2; ++rt)
    #pragma unroll
    for (int i = 0; i < 4; ++i) dmax[rt][i] = -__builtin_inff();

  #pragma unroll
  for (int ct = 0; ct < 32; ++ct) {
    const int rowc = ct * 16 + lm;
    const bf16x8 b0 = *reinterpret_cast<const bf16x8*>((const char*)cbBf + SWZ(rowc, 16 * g));
    const bf16x8 b1 = *reinterpret_cast<const bf16x8*>((const char*)cbBf + SWZ(rowc, 16 * g + 64));
    f32x4 a0 = (f32x4)0.0f, a1 = (f32x4)0.0f;
    a0 = __builtin_amdgcn_mfma_f32_16x16x32_bf16(afr[0][0], b0, a0, 0, 0, 0);
    a0 = __builtin_amdgcn_mfma_f32_16x16x32_bf16(afr[0][1], b1, a0, 0, 0, 0);
    a1 = __builtin_amdgcn_mfma_f32_16x16x32_bf16(afr[1][0], b0, a1, 0, 0, 0);
    a1 = __builtin_amdgcn_mfma_f32_16x16x32_bf16(afr[1][1], b1, a1, 0, 0, 0);
    #pragma unroll
    for (int i = 0; i < 4; ++i) {
      dmax[0][i] = fmaxf(dmax[0][i], a0[i]);
      dmax[1][i] = fmaxf(dmax[1][i], a1[i]);
    }
  }

  // ---- per-row max dot across the 16-lane (lm) group ----
  #pragma unroll
  for (int mask = 1; mask <= 8; mask <<= 1)
    #pragma unroll
    for (int rt = 0; rt < 2; ++rt)
      #pragma unroll
      for (int i = 0; i < 4; ++i)
        dmax[rt][i] = fmaxf(dmax[rt][i], __shfl_xor(dmax[rt][i], mask));

  // ---- thresholds: -2*dmax + CMAX + S*2^-15 + 1e-4 ----
  float thr[2][4];
  #pragma unroll
  for (int rt = 0; rt < 2; ++rt) {
    const float4 Sv = *reinterpret_cast<const float4*>(&SrowS[wv * 32 + rt * 16 + g * 4]);
    const float s4[4] = {Sv.x, Sv.y, Sv.z, Sv.w};
    #pragma unroll
    for (int i = 0; i < 4; ++i)
      thr[rt][i] = fmaf(-2.0f, dmax[rt][i],
                        fmaf(s4[i], 3.0517578125e-5f, 3.44140625e-4f));
  }

  // ---- Sweep 2: recompute (bit-identical), collect candidates ----
  unsigned c0 = 0, c1 = 0, c2 = 0, c3 = 0;
  int n = 0;
  #pragma unroll
  for (int ct = 0; ct < 32; ++ct) {
    const int rowc = ct * 16 + lm;
    const bf16x8 b0 = *reinterpret_cast<const bf16x8*>((const char*)cbBf + SWZ(rowc, 16 * g));
    const bf16x8 b1 = *reinterpret_cast<const bf16x8*>((const char*)cbBf + SWZ(rowc, 16 * g + 64));
    f32x4 a0 = (f32x4)0.0f, a1 = (f32x4)0.0f;
    a0 = __builtin_amdgcn_mfma_f32_16x16x32_bf16(afr[0][0], b0, a0, 0, 0, 0);
    a0 = __builtin_amdgcn_mfma_f32_16x16x32_bf16(afr[0][1], b1, a0, 0, 0, 0);
    a1 = __builtin_amdgcn_mfma_f32_16x16x32_bf16(afr[1][0], b0, a1, 0, 0, 0);
    a1 = __builtin_amdgcn_mfma_f32_16x16x32_bf16(afr[1][1], b1, a1, 0, 0, 0);
    const float Cc = cnormS[rowc];
    #pragma unroll
    for (int rt = 0; rt < 2; ++rt) {
      float core[4];
      #pragma unroll
      for (int i = 0; i < 4; ++i)
        core[i] = fmaf(-2.0f, (rt == 0 ? a0[i] : a1[i]), Cc);
      const float h = fmaxf(fmaxf(thr[rt][0] - core[0], thr[rt][1] - core[1]),
                            fmaxf(thr[rt][2] - core[2], thr[rt][3] - core[3]));
      if (__any(h >= 0.f)) {
        #pragma unroll
        for (int i = 0; i < 4; ++i) {
          if (core[i] <= thr[rt][i]) {
            const unsigned e = (unsigned)(ct * 8 + rt * 4 + i);
            if (n == 0) c0 = e; else if (n == 1) c1 = e;
            else if (n == 2) c2 = e; else if (n == 3) c3 = e;
            else {  // overflow -> per-wave queue (or immediate refine)
              const unsigned rec = e | ((unsigned)g << 8) | ((unsigned)lm << 12);
              const unsigned slot = atomicAdd(&ovfCnt[wv], 1u);
              if (slot < 64u) ovfQ[wv][slot] = rec;
              else refine_rk(row0, wv * 32 + rt * 16 + g * 4 + i, ct * 16 + lm,
                             z, cb, ArowS, cnormS, bestS);
            }
            ++n;
          }
        }
      }
    }
  }

  // ---- refine own candidates (<=4 in regs) ----
  const int nr = n < 4 ? n : 4;
  for (int t = 0; t < nr; ++t) {
    const unsigned e = (t == 0) ? c0 : (t == 1) ? c1 : (t == 2) ? c2 : c3;
    const int ct = (int)(e >> 3), rt = (int)((e >> 2) & 1u), i = (int)(e & 3u);
    refine_rk(row0, wv * 32 + rt * 16 + g * 4 + i, ct * 16 + lm,
              z, cb, ArowS, cnormS, bestS);
  }

  // ---- drain per-wave overflow queue (usually empty) ----
  {
    unsigned cnt = ovfCnt[wv];
    cnt = cnt < 64u ? cnt : 64u;
    for (unsigned idx = (unsigned)lane; idx < cnt; idx += 64u) {
      const unsigned rec = ovfQ[wv][idx];
      const unsigned e = rec & 255u;
      const int ct = (int)(e >> 3), rt = (int)((e >> 2) & 1u), i = (int)(e & 3u);
      const int g2 = (int)((rec >> 8) & 3u), lm2 = (int)((rec >> 12) & 15u);
      refine_rk(row0, wv * 32 + rt * 16 + g2 * 4 + i, ct * 16 + lm2,
                z, cb, ArowS, cnormS, bestS);
    }
  }

  // ---- write indices (wave-private rows; same-wave LDS ops are ordered) ----
  if (lane < 32) {
    const int r = wv * 32 + lane;
    out[row0 + r] = (int)(bestS[r] & 0xFFFFFFFFull);
  }
}

extern "C" void kernel_launch(void* const* d_in, const int* in_sizes, int n_in,
                              void* d_out, int out_size, void* d_ws, size_t ws_size,
                              hipStream_t stream) {
  const float* z  = (const float*)d_in[0];   // [N, 64] f32
  const float* cb = (const float*)d_in[1];   // [512, 64] f32
  int* out = (int*)d_out;                    // [N] int32 indices
  unsigned char* ws = (unsigned char*)d_ws;  // needs ~68 KiB

  const int N = in_sizes[0] / DCB;           // 262144

  vq_prep_kernel<<<2, 256, 0, stream>>>(cb, ws);
  vq_main_kernel<<<N / 256, 512, 0, stream>>>(z, cb, ws, out, N);
}